// Round 1
// baseline (347.730 us; speedup 1.0000x reference)
//
#include <hip/hip_runtime.h>

typedef unsigned short u16;
typedef __attribute__((ext_vector_type(8))) short short8;
typedef __attribute__((ext_vector_type(4))) float f32x4;
typedef __attribute__((ext_vector_type(4))) unsigned short u16x4;

__device__ __forceinline__ u16 f2b(float f) {
  unsigned u = __float_as_uint(f);
  unsigned r = (u + 0x7fffu + ((u >> 16) & 1u)) >> 16;
  return (u16)r;
}

// ---------------- conversion kernels ----------------
__global__ void cvt_bf16(const float* __restrict__ in, u16* __restrict__ out, int n) {
  int i = (blockIdx.x * blockDim.x + threadIdx.x) * 4;
  if (i >= n) return;
  f32x4 v = *(const f32x4*)(in + i);
  u16x4 o;
  o[0] = f2b(v[0]); o[1] = f2b(v[1]); o[2] = f2b(v[2]); o[3] = f2b(v[3]);
  *(u16x4*)(out + i) = o;
}

// in [R][C] f32 -> out [C][R] bf16
__global__ void transpose_cvt(const float* __restrict__ in, u16* __restrict__ out, int R, int C) {
  __shared__ float t[32][33];
  int c0 = blockIdx.x * 32, r0 = blockIdx.y * 32;
  int tx = threadIdx.x & 31, ty = threadIdx.x >> 5;
#pragma unroll
  for (int i = 0; i < 32; i += 8)
    t[ty + i][tx] = in[(size_t)(r0 + ty + i) * C + c0 + tx];
  __syncthreads();
#pragma unroll
  for (int i = 0; i < 32; i += 8)
    out[(size_t)(c0 + ty + i) * R + r0 + tx] = f2b(t[tx][ty + i]);
}

// ---------------- bf16 MFMA GEMM: C = A[M][1024] * Bt[N][1024]^T ----------------
// MODE 0: bf16 out row-major (ldc)        MODE 1: bf16 out [b][n][s] (v transposed)
// MODE 2: f32 out [m][1024] + bias
template <int MODE>
__global__ __launch_bounds__(256) void gemm_bt(
    const u16* __restrict__ A, const u16* __restrict__ Bt,
    u16* __restrict__ Cb, float* __restrict__ Cf, const float* __restrict__ bias,
    int Nvalid, int ldc) {
  __shared__ u16 As[128 * 32];
  __shared__ u16 Bs[128 * 32];
  const int tid = threadIdx.x;
  const int lane = tid & 63, wid = tid >> 6;
  const int lg = lane >> 4, li = lane & 15;
  const int wr = wid >> 1, wc = wid & 1;
  const int m0 = blockIdx.x * 128, n0 = blockIdx.y * 128;

  f32x4 acc[4][4] = {};

  const int srow = tid >> 2;        // 0..63
  const int skc = (tid & 3) * 8;    // 0,8,16,24

  for (int k0 = 0; k0 < 1024; k0 += 32) {
    __syncthreads();
#pragma unroll
    for (int it = 0; it < 2; ++it) {
      const int r = it * 64 + srow;
      short8 va = *(const short8*)(A + (size_t)(m0 + r) * 1024 + k0 + skc);
      int rb = n0 + r; rb = rb < Nvalid ? rb : Nvalid - 1;
      short8 vb = *(const short8*)(Bt + (size_t)rb * 1024 + k0 + skc);
      const int c = skc ^ ((r & 3) << 3);
      *(short8*)&As[r * 32 + c] = va;
      *(short8*)&Bs[r * 32 + c] = vb;
    }
    __syncthreads();
    short8 af[4], bfr[4];
#pragma unroll
    for (int mi = 0; mi < 4; ++mi) {
      const int r = wr * 64 + mi * 16 + li;
      af[mi] = *(const short8*)&As[r * 32 + ((lg * 8) ^ ((r & 3) << 3))];
    }
#pragma unroll
    for (int ni = 0; ni < 4; ++ni) {
      const int r = wc * 64 + ni * 16 + li;
      bfr[ni] = *(const short8*)&Bs[r * 32 + ((lg * 8) ^ ((r & 3) << 3))];
    }
#pragma unroll
    for (int mi = 0; mi < 4; ++mi)
#pragma unroll
      for (int ni = 0; ni < 4; ++ni)
        acc[mi][ni] = __builtin_amdgcn_mfma_f32_16x16x32_bf16(af[mi], bfr[ni], acc[mi][ni], 0, 0, 0);
  }

#pragma unroll
  for (int mi = 0; mi < 4; ++mi) {
#pragma unroll
    for (int ni = 0; ni < 4; ++ni) {
      const int n = n0 + wc * 64 + ni * 16 + li;
      if (n >= Nvalid) continue;
#pragma unroll
      for (int i = 0; i < 4; ++i) {
        const int m = m0 + wr * 64 + mi * 16 + lg * 4 + i;
        const float v = acc[mi][ni][i];
        if (MODE == 0) {
          Cb[(size_t)m * ldc + n] = f2b(v);
        } else if (MODE == 1) {
          Cb[((size_t)(m >> 10) * 64 + n) * 1024 + (m & 1023)] = f2b(v);
        } else {
          Cf[(size_t)m * 1024 + n] = v + bias[n];
        }
      }
    }
  }
}

// ---------------- causal MQA attention ----------------
// qb [8192][1024] bf16 (per head slice of 64), kb [b][s][64] bf16, vtb [b][64][1024] bf16
// ctx [8192][1024] bf16. Grid: (qtile=16, b=8, h=16), 256 thr (4 indep waves, 16 q-rows each).
__global__ __launch_bounds__(256) void attn_mqa(
    const u16* __restrict__ qb, const u16* __restrict__ kb,
    const u16* __restrict__ vtb, u16* __restrict__ ctxb) {
  const int qtile = blockIdx.x, b = blockIdx.y, h = blockIdx.z;
  const int tid = threadIdx.x, lane = tid & 63, wid = tid >> 6;
  const int lg = lane >> 4, li = lane & 15;
  const int q0 = qtile * 64 + wid * 16;

  __shared__ __align__(16) u16 p_lds[4][16][32];

  const u16* qrow = qb + (size_t)(b * 1024 + q0 + li) * 1024 + h * 64;
  const short8 aq0 = *(const short8*)(qrow + lg * 8);
  const short8 aq1 = *(const short8*)(qrow + 32 + lg * 8);

  f32x4 acc[4] = {};
  float m_i[4], l_i[4];
#pragma unroll
  for (int i = 0; i < 4; ++i) { m_i[i] = -1e30f; l_i[i] = 0.f; }

  for (int kv0 = 0; kv0 <= q0 + 15; kv0 += 32) {
    f32x4 s[2];
#pragma unroll
    for (int n = 0; n < 2; ++n) {
      const u16* kr = kb + (size_t)(b * 1024 + kv0 + n * 16 + li) * 64;
      const short8 bk0 = *(const short8*)(kr + lg * 8);
      const short8 bk1 = *(const short8*)(kr + 32 + lg * 8);
      f32x4 z = {};
      z = __builtin_amdgcn_mfma_f32_16x16x32_bf16(aq0, bk0, z, 0, 0, 0);
      z = __builtin_amdgcn_mfma_f32_16x16x32_bf16(aq1, bk1, z, 0, 0, 0);
      s[n] = z;
    }
    float pmax[4];
#pragma unroll
    for (int i = 0; i < 4; ++i) {
      const int row = q0 + lg * 4 + i;
#pragma unroll
      for (int n = 0; n < 2; ++n) {
        const int col = kv0 + n * 16 + li;
        float v = s[n][i] * 0.125f;   // 1/sqrt(64); mask->-inf commutes with scale
        if (col > row) v = -1e38f;
        s[n][i] = v;
      }
      pmax[i] = fmaxf(s[0][i], s[1][i]);
    }
#pragma unroll
    for (int off = 8; off >= 1; off >>= 1)
#pragma unroll
      for (int i = 0; i < 4; ++i)
        pmax[i] = fmaxf(pmax[i], __shfl_xor(pmax[i], off, 64));

    float rs[4];
#pragma unroll
    for (int i = 0; i < 4; ++i) {
      const float mnew = fmaxf(m_i[i], pmax[i]);
      const float corr = __expf(m_i[i] - mnew);  // first iter: exp(-1e30)=0, acc already 0
      m_i[i] = mnew;
      const float p0 = __expf(s[0][i] - mnew);
      const float p1 = __expf(s[1][i] - mnew);
      s[0][i] = p0; s[1][i] = p1;
      rs[i] = p0 + p1;
      l_i[i] *= corr;
#pragma unroll
      for (int n = 0; n < 4; ++n) acc[n][i] *= corr;
    }
#pragma unroll
    for (int off = 8; off >= 1; off >>= 1)
#pragma unroll
      for (int i = 0; i < 4; ++i)
        rs[i] += __shfl_xor(rs[i], off, 64);
#pragma unroll
    for (int i = 0; i < 4; ++i) l_i[i] += rs[i];

    // P (D-layout) -> LDS (XOR-swizzled) -> A-layout frag. Per-wave private, no barrier.
#pragma unroll
    for (int i = 0; i < 4; ++i) {
      const int row = lg * 4 + i;     // row&3 == i
      p_lds[wid][row][li ^ (i << 3)] = f2b(s[0][i]);
      p_lds[wid][row][(16 + li) ^ (i << 3)] = f2b(s[1][i]);
    }
    const short8 ap = *(const short8*)&p_lds[wid][li][(lg * 8) ^ ((li & 3) << 3)];
#pragma unroll
    for (int n = 0; n < 4; ++n) {
      const short8 bv = *(const short8*)(vtb + (size_t)(b * 64 + n * 16 + li) * 1024 + kv0 + lg * 8);
      acc[n] = __builtin_amdgcn_mfma_f32_16x16x32_bf16(ap, bv, acc[n], 0, 0, 0);
    }
  }

#pragma unroll
  for (int n = 0; n < 4; ++n) {
#pragma unroll
    for (int i = 0; i < 4; ++i) {
      const int m = b * 1024 + q0 + lg * 4 + i;
      const int c = h * 64 + n * 16 + li;
      ctxb[(size_t)m * 1024 + c] = f2b(acc[n][i] / l_i[i]);
    }
  }
}

// ---------------- host launch ----------------
extern "C" void kernel_launch(void* const* d_in, const int* in_sizes, int n_in,
                              void* d_out, int out_size, void* d_ws, size_t ws_size,
                              hipStream_t stream) {
  const float* x  = (const float*)d_in[0];
  const float* Wq = (const float*)d_in[1];
  const float* Wk = (const float*)d_in[2];
  const float* Wv = (const float*)d_in[3];
  const float* Wo = (const float*)d_in[4];
  const float* bo = (const float*)d_in[5];
  float* out = (float*)d_out;

  u16* xb  = (u16*)d_ws;                 // [8192][1024]
  u16* wqT = xb  + (size_t)8192 * 1024;  // [1024][1024]
  u16* wkT = wqT + (size_t)1024 * 1024;  // [64][1024]
  u16* wvT = wkT + (size_t)64 * 1024;    // [64][1024]
  u16* woT = wvT + (size_t)64 * 1024;    // [1024][1024]
  u16* qbf = woT + (size_t)1024 * 1024;  // [8192][1024]
  u16* kbf = qbf + (size_t)8192 * 1024;  // [8192][64]
  u16* vtb = kbf + (size_t)8192 * 64;    // [8][64][1024]
  u16* ctx = vtb + (size_t)8 * 64 * 1024;// [8192][1024]   total ~54.3 MB of ws

  cvt_bf16<<<8192, 256, 0, stream>>>(x, xb, 8192 * 1024);
  transpose_cvt<<<dim3(32, 32), 256, 0, stream>>>(Wq, wqT, 1024, 1024);
  transpose_cvt<<<dim3(2, 32), 256, 0, stream>>>(Wk, wkT, 1024, 64);
  transpose_cvt<<<dim3(2, 32), 256, 0, stream>>>(Wv, wvT, 1024, 64);
  transpose_cvt<<<dim3(32, 32), 256, 0, stream>>>(Wo, woT, 1024, 1024);

  gemm_bt<0><<<dim3(64, 8), 256, 0, stream>>>(xb, wqT, qbf, nullptr, nullptr, 1024, 1024);
  gemm_bt<0><<<dim3(64, 1), 256, 0, stream>>>(xb, wkT, kbf, nullptr, nullptr, 64, 64);
  gemm_bt<1><<<dim3(64, 1), 256, 0, stream>>>(xb, wvT, vtb, nullptr, nullptr, 64, 0);

  attn_mqa<<<dim3(16, 8, 16), 256, 0, stream>>>(qbf, kbf, vtb, ctx);

  gemm_bt<2><<<dim3(64, 8), 256, 0, stream>>>(ctx, woT, nullptr, out, bo, 1024, 0);
}

// Round 2
// 196.638 us; speedup vs baseline: 1.7684x; 1.7684x over previous
//
#include <hip/hip_runtime.h>

typedef unsigned short u16;
typedef __attribute__((ext_vector_type(8))) short short8;
typedef __attribute__((ext_vector_type(4))) short short4v;
typedef __attribute__((ext_vector_type(4))) float f32x4;
typedef __attribute__((ext_vector_type(16))) float f32x16;
typedef __attribute__((ext_vector_type(4))) unsigned short u16x4;
typedef __attribute__((ext_vector_type(4))) int i32x4;

__device__ __forceinline__ u16 f2b(float f) {
  unsigned u = __float_as_uint(f);
  unsigned r = (u + 0x7fffu + ((u >> 16) & 1u)) >> 16;
  return (u16)r;
}

// ---------------- conversion kernels ----------------
__global__ void cvt_bf16(const float* __restrict__ in, u16* __restrict__ out, int n) {
  int i = (blockIdx.x * blockDim.x + threadIdx.x) * 4;
  if (i >= n) return;
  f32x4 v = *(const f32x4*)(in + i);
  u16x4 o;
  o[0] = f2b(v[0]); o[1] = f2b(v[1]); o[2] = f2b(v[2]); o[3] = f2b(v[3]);
  *(u16x4*)(out + i) = o;
}

// in [R][C] f32 -> out [C][R] bf16
__global__ void transpose_cvt(const float* __restrict__ in, u16* __restrict__ out, int R, int C) {
  __shared__ float t[32][33];
  int c0 = blockIdx.x * 32, r0 = blockIdx.y * 32;
  int tx = threadIdx.x & 31, ty = threadIdx.x >> 5;
#pragma unroll
  for (int i = 0; i < 32; i += 8)
    t[ty + i][tx] = in[(size_t)(r0 + ty + i) * C + c0 + tx];
  __syncthreads();
#pragma unroll
  for (int i = 0; i < 32; i += 8)
    out[(size_t)(c0 + ty + i) * R + r0 + tx] = f2b(t[tx][ty + i]);
}

// ---------------- bf16 MFMA GEMM: C = A[M][1024] * Bt[N][1024]^T ----------------
// MODE 0: bf16 out row-major (ldc), scaled by `scale`
// MODE 2: f32 out [m][1024] + bias
// MODE 3: split: n<64 -> Cb [m][64] row-major (K); n>=64 -> Cb2 [b][n-64][s] (V^T)
template <int MODE>
__global__ __launch_bounds__(256) void gemm_bt(
    const u16* __restrict__ A, const u16* __restrict__ Bt,
    u16* __restrict__ Cb, u16* __restrict__ Cb2, float* __restrict__ Cf,
    const float* __restrict__ bias, float scale, int Nvalid, int ldc) {
  __shared__ u16 As[128 * 32];
  __shared__ u16 Bs[128 * 32];
  const int tid = threadIdx.x;
  const int lane = tid & 63, wid = tid >> 6;
  const int lg = lane >> 4, li = lane & 15;
  const int wr = wid >> 1, wc = wid & 1;
  const int m0 = blockIdx.x * 128, n0 = blockIdx.y * 128;

  f32x4 acc[4][4] = {};

  const int srow = tid >> 2;        // 0..63
  const int skc = (tid & 3) * 8;    // 0,8,16,24

  for (int k0 = 0; k0 < 1024; k0 += 32) {
    __syncthreads();
#pragma unroll
    for (int it = 0; it < 2; ++it) {
      const int r = it * 64 + srow;
      short8 va = *(const short8*)(A + (size_t)(m0 + r) * 1024 + k0 + skc);
      int rb = n0 + r; rb = rb < Nvalid ? rb : Nvalid - 1;
      short8 vb = *(const short8*)(Bt + (size_t)rb * 1024 + k0 + skc);
      const int c = skc ^ ((r & 3) << 3);
      *(short8*)&As[r * 32 + c] = va;
      *(short8*)&Bs[r * 32 + c] = vb;
    }
    __syncthreads();
    short8 af[4], bfr[4];
#pragma unroll
    for (int mi = 0; mi < 4; ++mi) {
      const int r = wr * 64 + mi * 16 + li;
      af[mi] = *(const short8*)&As[r * 32 + ((lg * 8) ^ ((r & 3) << 3))];
    }
#pragma unroll
    for (int ni = 0; ni < 4; ++ni) {
      const int r = wc * 64 + ni * 16 + li;
      bfr[ni] = *(const short8*)&Bs[r * 32 + ((lg * 8) ^ ((r & 3) << 3))];
    }
#pragma unroll
    for (int mi = 0; mi < 4; ++mi)
#pragma unroll
      for (int ni = 0; ni < 4; ++ni)
        acc[mi][ni] = __builtin_amdgcn_mfma_f32_16x16x32_bf16(af[mi], bfr[ni], acc[mi][ni], 0, 0, 0);
  }

#pragma unroll
  for (int mi = 0; mi < 4; ++mi) {
#pragma unroll
    for (int ni = 0; ni < 4; ++ni) {
      const int n = n0 + wc * 64 + ni * 16 + li;
      if (n >= Nvalid) continue;
#pragma unroll
      for (int i = 0; i < 4; ++i) {
        const int m = m0 + wr * 64 + mi * 16 + lg * 4 + i;
        const float v = acc[mi][ni][i];
        if (MODE == 0) {
          Cb[(size_t)m * ldc + n] = f2b(v * scale);
        } else if (MODE == 2) {
          Cf[(size_t)m * 1024 + n] = v + bias[n];
        } else {  // MODE 3
          if (n < 64) Cb[(size_t)m * 64 + n] = f2b(v);
          else Cb2[((size_t)(m >> 10) * 64 + (n - 64)) * 1024 + (m & 1023)] = f2b(v);
        }
      }
    }
  }
}

// ---------------- causal MQA attention, swapped-operand 32x32 ----------------
// qb [8192][1024] bf16 (Q pre-scaled by 0.125*log2e), kb [b*1024][64] bf16,
// vtb [b][64][1024] bf16, ctx [8192][1024] bf16.
// Grid (4, 8, 16), 256 thr = 4 indep waves. Wave w handles q-tiles {w, 31-w}
// (32 rows each) -> uniform 33 kv-iterations per wave. No LDS, no barriers.
__global__ __launch_bounds__(256) void attn_mqa2(
    const u16* __restrict__ qb, const u16* __restrict__ kb,
    const u16* __restrict__ vtb, u16* __restrict__ ctxb) {
  const int b = blockIdx.y, h = blockIdx.z;
  const int lane = threadIdx.x & 63, wid = threadIdx.x >> 6;
  const int w = blockIdx.x * 4 + wid;     // 0..15
  const int l31 = lane & 31, hi = lane >> 5;

  const u16* kbb = kb + (size_t)b * 1024 * 64;
  const u16* vbb = vtb + (size_t)b * 64 * 1024;

#pragma unroll
  for (int halfi = 0; halfi < 2; ++halfi) {
    const int qt = halfi == 0 ? w : 31 - w;
    const int q0 = qt * 32;

    // Q fragments (B-operand): row = q = l31, d = t*16 + hi*8 + j
    const u16* qrow = qb + (size_t)(b * 1024 + q0 + l31) * 1024 + h * 64 + hi * 8;
    short8 qa[4];
#pragma unroll
    for (int t = 0; t < 4; ++t) qa[t] = *(const short8*)(qrow + t * 16);

    f32x16 acc0 = {}, acc1 = {};
    float m_r = -1e30f, lsum = 0.f;

    for (int kvt = 0; kvt <= qt; ++kvt) {
      const int kv0 = kvt * 32;
      // S^T = K * Q^T  (both operands use identical d-addressing -> layout-safe)
      const u16* krow = kbb + (size_t)(kv0 + l31) * 64 + hi * 8;
      f32x16 st = {};
#pragma unroll
      for (int t = 0; t < 4; ++t) {
        short8 ka = *(const short8*)(krow + t * 16);
        st = __builtin_amdgcn_mfma_f32_32x32x16_bf16(ka, qa[t], st, 0, 0, 0);
      }
      // lane holds S[kv0+crow(r,hi)][q0+l31], crow = (r&3)+8*(r>>2)+4*hi
      if (kvt == qt) {  // diagonal tile: mask kv > q
#pragma unroll
        for (int r = 0; r < 16; ++r) {
          const int crow = (r & 3) + 8 * (r >> 2) + 4 * hi;
          if (crow > l31) st[r] = -1e38f;
        }
      }
      float pm = st[0];
#pragma unroll
      for (int r = 1; r < 16; ++r) pm = fmaxf(pm, st[r]);
      pm = fmaxf(pm, __shfl_xor(pm, 32, 64));   // partner holds other 16 kv
      if (__any(pm > m_r + 8.0f)) {             // defer-max (T13), log2 units
        const float mnew = fmaxf(m_r, pm);
        const float corr = exp2f(m_r - mnew);
        m_r = mnew;
        lsum *= corr;
#pragma unroll
        for (int r = 0; r < 16; ++r) { acc0[r] *= corr; acc1[r] *= corr; }
      }
#pragma unroll
      for (int r = 0; r < 16; ++r) {
        st[r] = exp2f(st[r] - m_r);   // Q pre-scaled by 0.125*log2e
        lsum += st[r];
      }
      // P -> bf16 A-frags. pa[ks] slot j = st[8ks+j] covers k=16ks+g(hi,j),
      // g(hi,j) = 4hi+(j&3)+8*(j>>2) (bijective per mfma); V uses same g.
      unsigned pw0, pw1, pw2, pw3, pw4, pw5, pw6, pw7;
      asm("v_cvt_pk_bf16_f32 %0, %1, %2" : "=v"(pw0) : "v"(st[0]),  "v"(st[1]));
      asm("v_cvt_pk_bf16_f32 %0, %1, %2" : "=v"(pw1) : "v"(st[2]),  "v"(st[3]));
      asm("v_cvt_pk_bf16_f32 %0, %1, %2" : "=v"(pw2) : "v"(st[4]),  "v"(st[5]));
      asm("v_cvt_pk_bf16_f32 %0, %1, %2" : "=v"(pw3) : "v"(st[6]),  "v"(st[7]));
      asm("v_cvt_pk_bf16_f32 %0, %1, %2" : "=v"(pw4) : "v"(st[8]),  "v"(st[9]));
      asm("v_cvt_pk_bf16_f32 %0, %1, %2" : "=v"(pw5) : "v"(st[10]), "v"(st[11]));
      asm("v_cvt_pk_bf16_f32 %0, %1, %2" : "=v"(pw6) : "v"(st[12]), "v"(st[13]));
      asm("v_cvt_pk_bf16_f32 %0, %1, %2" : "=v"(pw7) : "v"(st[14]), "v"(st[15]));
      i32x4 w0 = {(int)pw0, (int)pw1, (int)pw2, (int)pw3};
      i32x4 w1 = {(int)pw4, (int)pw5, (int)pw6, (int)pw7};
      const short8 pa0 = *(const short8*)&w0;
      const short8 pa1 = *(const short8*)&w1;

      // PV: ctx[q][d] += P[q][kv] * V[kv][d]; B rows = d from vtb [b][d][s]
#pragma unroll
      for (int dt = 0; dt < 2; ++dt) {
        const u16* vrow = vbb + (size_t)(dt * 32 + l31) * 1024 + kv0 + hi * 4;
#pragma unroll
        for (int ks = 0; ks < 2; ++ks) {
          short4v lo = *(const short4v*)(vrow + ks * 16);
          short4v hh = *(const short4v*)(vrow + ks * 16 + 8);
          short8 vb = {lo[0], lo[1], lo[2], lo[3], hh[0], hh[1], hh[2], hh[3]};
          if (dt == 0)
            acc0 = __builtin_amdgcn_mfma_f32_32x32x16_bf16(ks ? pa1 : pa0, vb, acc0, 0, 0, 0);
          else
            acc1 = __builtin_amdgcn_mfma_f32_32x32x16_bf16(ks ? pa1 : pa0, vb, acc1, 0, 0, 0);
        }
      }
    }

    const float lfull = lsum + __shfl_xor(lsum, 32, 64);
    const float linv = 1.0f / lfull;
#pragma unroll
    for (int r = 0; r < 16; ++r) {
      const int crow = (r & 3) + 8 * (r >> 2) + 4 * hi;
      const float lr = __shfl(linv, crow, 64);
      const size_t orow = (size_t)(b * 1024 + q0 + crow) * 1024 + h * 64;
      ctxb[orow + l31] = f2b(acc0[r] * lr);
      ctxb[orow + 32 + l31] = f2b(acc1[r] * lr);
    }
  }
}

// ---------------- host launch ----------------
extern "C" void kernel_launch(void* const* d_in, const int* in_sizes, int n_in,
                              void* d_out, int out_size, void* d_ws, size_t ws_size,
                              hipStream_t stream) {
  const float* x  = (const float*)d_in[0];
  const float* Wq = (const float*)d_in[1];
  const float* Wk = (const float*)d_in[2];
  const float* Wv = (const float*)d_in[3];
  const float* Wo = (const float*)d_in[4];
  const float* bo = (const float*)d_in[5];
  float* out = (float*)d_out;

  u16* xb  = (u16*)d_ws;                 // [8192][1024]
  u16* wqT = xb  + (size_t)8192 * 1024;  // [1024][1024]
  u16* wkT = wqT + (size_t)1024 * 1024;  // [64][1024]  (K weights, row-major B^T)
  u16* wvT = wkT + (size_t)64 * 1024;    // [64][1024]  (V weights, contiguous after K)
  u16* woT = wvT + (size_t)64 * 1024;    // [1024][1024]
  u16* qbf = woT + (size_t)1024 * 1024;  // [8192][1024] (pre-scaled)
  u16* kbf = qbf + (size_t)8192 * 1024;  // [8192][64]
  u16* vtb = kbf + (size_t)8192 * 64;    // [8][64][1024]
  u16* ctx = vtb + (size_t)8 * 64 * 1024;// [8192][1024]

  cvt_bf16<<<8192, 256, 0, stream>>>(x, xb, 8192 * 1024);
  transpose_cvt<<<dim3(32, 32), 256, 0, stream>>>(Wq, wqT, 1024, 1024);
  transpose_cvt<<<dim3(2, 32), 256, 0, stream>>>(Wk, wkT, 1024, 64);
  transpose_cvt<<<dim3(2, 32), 256, 0, stream>>>(Wv, wvT, 1024, 64);
  transpose_cvt<<<dim3(32, 32), 256, 0, stream>>>(Wo, woT, 1024, 1024);

  const float SCL = 0.125f * 1.44269504088896340736f;  // fold 1/sqrt(Dh) * log2(e) into Q
  gemm_bt<0><<<dim3(64, 8), 256, 0, stream>>>(xb, wqT, qbf, nullptr, nullptr, nullptr, SCL, 1024, 1024);
  gemm_bt<3><<<dim3(64, 1), 256, 0, stream>>>(xb, wkT, kbf, vtb, nullptr, nullptr, 1.f, 128, 0);

  attn_mqa2<<<dim3(4, 8, 16), 256, 0, stream>>>(qbf, kbf, vtb, ctx);

  gemm_bt<2><<<dim3(64, 8), 256, 0, stream>>>(ctx, woT, nullptr, nullptr, out, bo, 1.f, 1024, 0);
}

// Round 3
// 142.902 us; speedup vs baseline: 2.4333x; 1.3760x over previous
//
#include <hip/hip_runtime.h>

typedef unsigned short u16;
typedef __attribute__((ext_vector_type(8))) short short8;
typedef __attribute__((ext_vector_type(4))) float f32x4;
typedef __attribute__((ext_vector_type(16))) float f32x16;
typedef __attribute__((ext_vector_type(4))) unsigned short u16x4;
typedef __attribute__((ext_vector_type(4))) int i32x4;

__device__ __forceinline__ u16 f2b(float f) {
  unsigned u = __float_as_uint(f);
  unsigned r = (u + 0x7fffu + ((u >> 16) & 1u)) >> 16;
  return (u16)r;
}

__device__ __forceinline__ void gload16(const u16* g, u16* l) {
  __builtin_amdgcn_global_load_lds((const __attribute__((address_space(1))) void*)g,
                                   (__attribute__((address_space(3))) void*)l, 16, 0, 0);
}

// ---------------- conversion kernels ----------------
__global__ void cvt_bf16(const float* __restrict__ in, u16* __restrict__ out, int n) {
  int i = (blockIdx.x * blockDim.x + threadIdx.x) * 4;
  if (i >= n) return;
  f32x4 v = *(const f32x4*)(in + i);
  u16x4 o;
  o[0] = f2b(v[0]); o[1] = f2b(v[1]); o[2] = f2b(v[2]); o[3] = f2b(v[3]);
  *(u16x4*)(out + i) = o;
}

// in [R][C] f32 -> out [C][R] bf16
__global__ void transpose_cvt(const float* __restrict__ in, u16* __restrict__ out, int R, int C) {
  __shared__ float t[32][33];
  int c0 = blockIdx.x * 32, r0 = blockIdx.y * 32;
  int tx = threadIdx.x & 31, ty = threadIdx.x >> 5;
#pragma unroll
  for (int i = 0; i < 32; i += 8)
    t[ty + i][tx] = in[(size_t)(r0 + ty + i) * C + c0 + tx];
  __syncthreads();
#pragma unroll
  for (int i = 0; i < 32; i += 8)
    out[(size_t)(c0 + ty + i) * R + r0 + tx] = f2b(t[tx][ty + i]);
}

// ---------------- bf16 MFMA GEMM: C = A[M][1024] * Bt[N][1024]^T ----------------
// MODE 0: bf16 out row-major ld=1024, scaled     MODE 2: f32 out [m][1024] + bias
// MODE 3: n<64 -> K packed frag layout; n>=64 -> V packed frag layout
template <int MODE>
__global__ __launch_bounds__(256) void gemm_bt(
    const u16* __restrict__ A, const u16* __restrict__ Bt,
    u16* __restrict__ Cb, u16* __restrict__ Cb2, float* __restrict__ Cf,
    const float* __restrict__ bias, float scale) {
  __shared__ u16 As[4096];
  __shared__ u16 Bs[4096];
  const int tid = threadIdx.x;
  const int lane = tid & 63, wid = tid >> 6;
  const int lg = lane >> 4, li = lane & 15;
  const int wr = wid >> 1, wc = wid & 1;
  const int m0 = blockIdx.x * 128, n0 = blockIdx.y * 128;

  f32x4 acc[4][4] = {};

  const int srow = tid >> 2;                    // 0..63
  const int skc = (tid & 3) * 8;                // 0,8,16,24
  const int asrc = skc ^ ((srow & 3) << 3);     // pre-swizzled source col
  const u16* Ab = A + (size_t)(m0 + srow) * 1024 + asrc;
  const u16* Bb = Bt + (size_t)(n0 + srow) * 1024 + asrc;
  u16* AsW = As + wid * 512;   // lane-linear dest: base + lane*16B
  u16* BsW = Bs + wid * 512;

  for (int k0 = 0; k0 < 1024; k0 += 32) {
    __syncthreads();
    gload16(Ab + k0,         AsW);
    gload16(Ab + 65536 + k0, AsW + 2048);
    gload16(Bb + k0,         BsW);
    gload16(Bb + 65536 + k0, BsW + 2048);
    __syncthreads();   // drains vmcnt -> staged data visible
    short8 af[4], bfr[4];
#pragma unroll
    for (int mi = 0; mi < 4; ++mi) {
      const int r = wr * 64 + mi * 16 + li;
      af[mi] = *(const short8*)&As[r * 32 + ((lg * 8) ^ ((r & 3) << 3))];
    }
#pragma unroll
    for (int ni = 0; ni < 4; ++ni) {
      const int r = wc * 64 + ni * 16 + li;
      bfr[ni] = *(const short8*)&Bs[r * 32 + ((lg * 8) ^ ((r & 3) << 3))];
    }
#pragma unroll
    for (int mi = 0; mi < 4; ++mi)
#pragma unroll
      for (int ni = 0; ni < 4; ++ni)
        acc[mi][ni] = __builtin_amdgcn_mfma_f32_16x16x32_bf16(af[mi], bfr[ni], acc[mi][ni], 0, 0, 0);
  }

#pragma unroll
  for (int mi = 0; mi < 4; ++mi) {
#pragma unroll
    for (int ni = 0; ni < 4; ++ni) {
      const int n = n0 + wc * 64 + ni * 16 + li;
#pragma unroll
      for (int i = 0; i < 4; ++i) {
        const int m = m0 + wr * 64 + mi * 16 + lg * 4 + i;
        const float v = acc[mi][ni][i];
        if (MODE == 0) {
          Cb[(size_t)m * 1024 + n] = f2b(v * scale);
        } else if (MODE == 2) {
          Cf[(size_t)m * 1024 + n] = v + bias[n];
        } else {  // MODE 3: packed fragment layouts for attention
          const int bb = m >> 10, ss = m & 1023;
          const int kvt = ss >> 5, sl = ss & 31;
          if (n < 64) {
            const int t = n >> 4, h2 = (n >> 3) & 1, j = n & 7;
            Cb[(((((size_t)bb * 32 + kvt) * 4 + t) * 2 + h2) * 32 + sl) * 8 + j] = f2b(v);
          } else {
            const int d = n - 64;
            const int ks = sl >> 4, rem = sl & 15;
            const int h2 = (rem >> 2) & 1, j = (rem & 3) | ((rem >> 3) << 2);
            Cb2[(((((size_t)bb * 32 + kvt) * 2 + ks) * 2 + h2) * 64 + d) * 8 + j] = f2b(v);
          }
        }
      }
    }
  }
}

// ---------------- causal MQA attention, kv-split=2 flash-decoding ----------------
// Grid (8,8,16) x 256. Wave task: c=bx*4+wid in [0,32): pair p=c>>1, split s=c&1.
// Handles qt in {p, 31-p}, kv-range half s. Writes unnormalized partials.
__global__ __launch_bounds__(256, 4) void attn_mqa3(
    const u16* __restrict__ qb, const u16* __restrict__ k3,
    const u16* __restrict__ vt3, u16* __restrict__ paro, float* __restrict__ pml) {
  const int b = blockIdx.y, h = blockIdx.z;
  const int lane = threadIdx.x & 63, wid = threadIdx.x >> 6;
  const int c = blockIdx.x * 4 + wid;
  const int p = c >> 1, s = c & 1;
  const int l31 = lane & 31, hi = lane >> 5;

  const u16* k3b = k3 + (size_t)b * 65536;
  const u16* v3b = vt3 + (size_t)b * 65536;

#pragma unroll
  for (int halfi = 0; halfi < 2; ++halfi) {
    const int qt = halfi ? 31 - p : p;
    const int q0 = qt * 32;
    const int n0t = (qt + 2) >> 1;             // ceil((qt+1)/2)
    const int kb_ = s ? n0t : 0;
    const int ke = s ? qt + 1 : n0t;
    const int task = (b * 16 + h) * 32 + qt;

    const u16* qrow = qb + (size_t)(b * 1024 + q0 + l31) * 1024 + h * 64 + hi * 8;
    short8 qa[4];
#pragma unroll
    for (int t = 0; t < 4; ++t) qa[t] = *(const short8*)(qrow + t * 16);

    f32x16 acc0 = {}, acc1 = {};
    float m_r = -1e30f, lsum = 0.f;

    if (kb_ < ke) {
      short8 kc[4], kn[4];
      const u16* kt0 = k3b + (size_t)kb_ * 2048 + l31 * 8;
#pragma unroll
      for (int t = 0; t < 4; ++t) kc[t] = *(const short8*)(kt0 + (t * 2 + hi) * 256);

      for (int kvt = kb_; kvt < ke; ++kvt) {
        const bool hasnext = (kvt + 1 < ke);
        const u16* ktn = k3b + (size_t)(kvt + 1) * 2048 + l31 * 8;
        if (hasnext) {
#pragma unroll
          for (int t = 0; t < 4; ++t) kn[t] = *(const short8*)(ktn + (t * 2 + hi) * 256);
        }
        const u16* vtt = v3b + (size_t)kvt * 2048 + hi * 512 + l31 * 8;
        const short8 vf0 = *(const short8*)(vtt);          // ks0,dt0
        const short8 vf1 = *(const short8*)(vtt + 1024);   // ks1,dt0
        const short8 vf2 = *(const short8*)(vtt + 256);    // ks0,dt1
        const short8 vf3 = *(const short8*)(vtt + 1280);   // ks1,dt1

        f32x16 st = {};
#pragma unroll
        for (int t = 0; t < 4; ++t)
          st = __builtin_amdgcn_mfma_f32_32x32x16_bf16(kc[t], qa[t], st, 0, 0, 0);

        if (kvt == qt) {  // diagonal: mask kv > q
#pragma unroll
          for (int r = 0; r < 16; ++r) {
            const int crow = (r & 3) + 8 * (r >> 2) + 4 * hi;
            if (crow > l31) st[r] = -1e38f;
          }
        }
        // row-max tree (q = l31 per lane)
        float x0 = fmaxf(st[0], st[1]),   x1 = fmaxf(st[2], st[3]);
        float x2 = fmaxf(st[4], st[5]),   x3 = fmaxf(st[6], st[7]);
        float x4 = fmaxf(st[8], st[9]),   x5 = fmaxf(st[10], st[11]);
        float x6 = fmaxf(st[12], st[13]), x7 = fmaxf(st[14], st[15]);
        x0 = fmaxf(x0, x1); x2 = fmaxf(x2, x3); x4 = fmaxf(x4, x5); x6 = fmaxf(x6, x7);
        float pm = fmaxf(fmaxf(x0, x2), fmaxf(x4, x6));
        pm = fmaxf(pm, __shfl_xor(pm, 32, 64));
        if (__any(pm > m_r + 8.0f)) {   // defer-max (log2 domain)
          const float mnew = fmaxf(m_r, pm);
          float corr;
          asm("v_exp_f32 %0, %1" : "=v"(corr) : "v"(m_r - mnew));
          m_r = mnew;
          lsum *= corr;
#pragma unroll
          for (int r = 0; r < 16; ++r) { acc0[r] *= corr; acc1[r] *= corr; }
        }
        float e[16];
#pragma unroll
        for (int r = 0; r < 16; ++r) {
          const float dd = st[r] - m_r;
          asm("v_exp_f32 %0, %1" : "=v"(e[r]) : "v"(dd));
        }
        lsum += ((e[0] + e[1]) + (e[2] + e[3])) + ((e[4] + e[5]) + (e[6] + e[7])) +
                (((e[8] + e[9]) + (e[10] + e[11])) + ((e[12] + e[13]) + (e[14] + e[15])));

        unsigned pw0, pw1, pw2, pw3, pw4, pw5, pw6, pw7;
        asm("v_cvt_pk_bf16_f32 %0, %1, %2" : "=v"(pw0) : "v"(e[0]),  "v"(e[1]));
        asm("v_cvt_pk_bf16_f32 %0, %1, %2" : "=v"(pw1) : "v"(e[2]),  "v"(e[3]));
        asm("v_cvt_pk_bf16_f32 %0, %1, %2" : "=v"(pw2) : "v"(e[4]),  "v"(e[5]));
        asm("v_cvt_pk_bf16_f32 %0, %1, %2" : "=v"(pw3) : "v"(e[6]),  "v"(e[7]));
        asm("v_cvt_pk_bf16_f32 %0, %1, %2" : "=v"(pw4) : "v"(e[8]),  "v"(e[9]));
        asm("v_cvt_pk_bf16_f32 %0, %1, %2" : "=v"(pw5) : "v"(e[10]), "v"(e[11]));
        asm("v_cvt_pk_bf16_f32 %0, %1, %2" : "=v"(pw6) : "v"(e[12]), "v"(e[13]));
        asm("v_cvt_pk_bf16_f32 %0, %1, %2" : "=v"(pw7) : "v"(e[14]), "v"(e[15]));
        i32x4 w0 = {(int)pw0, (int)pw1, (int)pw2, (int)pw3};
        i32x4 w1 = {(int)pw4, (int)pw5, (int)pw6, (int)pw7};
        const short8 pa0 = *(const short8*)&w0;
        const short8 pa1 = *(const short8*)&w1;

        acc0 = __builtin_amdgcn_mfma_f32_32x32x16_bf16(pa0, vf0, acc0, 0, 0, 0);
        acc0 = __builtin_amdgcn_mfma_f32_32x32x16_bf16(pa1, vf1, acc0, 0, 0, 0);
        acc1 = __builtin_amdgcn_mfma_f32_32x32x16_bf16(pa0, vf2, acc1, 0, 0, 0);
        acc1 = __builtin_amdgcn_mfma_f32_32x32x16_bf16(pa1, vf3, acc1, 0, 0, 0);

        if (hasnext) { kc[0] = kn[0]; kc[1] = kn[1]; kc[2] = kn[2]; kc[3] = kn[3]; }
      }
    }

    const float lfull = lsum + __shfl_xor(lsum, 32, 64);
    u16* pbase = paro + ((size_t)task * 2 + s) * 2048;
#pragma unroll
    for (int r = 0; r < 16; ++r) {
      const int crow = (r & 3) + 8 * (r >> 2) + 4 * hi;
      pbase[crow * 64 + l31] = f2b(acc0[r]);
      pbase[crow * 64 + 32 + l31] = f2b(acc1[r]);
    }
    if (hi == 0) {
      const size_t pidx = ((size_t)task * 2 + s) * 2;
      pml[(pidx + 0) * 32 + l31] = m_r;
      pml[(pidx + 1) * 32 + l31] = lfull;
    }
  }
}

// ---------------- combine the two kv-splits ----------------
__global__ __launch_bounds__(64) void attn_combine(
    const u16* __restrict__ paro, const float* __restrict__ pml, u16* __restrict__ ctxb) {
  const int task = blockIdx.x;
  const int d = threadIdx.x;
  const int qt = task & 31, hh = (task >> 5) & 15, bb = task >> 9;
  const u16* p0 = paro + (size_t)task * 4096;
  const u16* p1 = p0 + 2048;
  const float* q0m = pml + (size_t)task * 128;  // [s][{m,l}][32]
#pragma unroll 4
  for (int r = 0; r < 32; ++r) {
    const float m0 = q0m[r], l0 = q0m[32 + r], m1 = q0m[64 + r], l1 = q0m[96 + r];
    const float M = fmaxf(m0, m1);
    float w0c, w1c;
    asm("v_exp_f32 %0, %1" : "=v"(w0c) : "v"(m0 - M));
    asm("v_exp_f32 %0, %1" : "=v"(w1c) : "v"(m1 - M));
    const float den = w0c * l0 + w1c * l1;
    const float o0 = __uint_as_float((unsigned)p0[r * 64 + d] << 16);
    const float o1 = __uint_as_float((unsigned)p1[r * 64 + d] << 16);
    const float val = (w0c * o0 + w1c * o1) / den;
    ctxb[((size_t)(bb * 1024 + qt * 32 + r)) * 1024 + hh * 64 + d] = f2b(val);
  }
}

// ---------------- host launch ----------------
extern "C" void kernel_launch(void* const* d_in, const int* in_sizes, int n_in,
                              void* d_out, int out_size, void* d_ws, size_t ws_size,
                              hipStream_t stream) {
  const float* x  = (const float*)d_in[0];
  const float* Wq = (const float*)d_in[1];
  const float* Wk = (const float*)d_in[2];
  const float* Wv = (const float*)d_in[3];
  const float* Wo = (const float*)d_in[4];
  const float* bo = (const float*)d_in[5];
  float* out = (float*)d_out;

  // workspace layout (u16 elements), with lifetime overlays; total 27M u16 = 54MB
  u16* ws16 = (u16*)d_ws;
  const size_t M1 = 1u << 20;
  u16* woT  = ws16;                  // [0,1M)
  u16* qbf  = ws16 + 1 * M1;         // [1M,9M)   Q; later reused as ctx
  u16* k3   = ws16 + 9 * M1;         // [9M,9.5M)
  u16* vt3  = ws16 + 9 * M1 + (M1 >> 1);  // [9.5M,10M)
  u16* xb   = ws16 + 10 * M1;        // [10M,18M)
  u16* wqT  = ws16 + 18 * M1;        // [18M,19M)
  u16* wkT  = ws16 + 19 * M1;        // [19M,19.0625M)  (wvT contiguous after)
  u16* wvT  = wkT + 65536;
  u16* paro = ws16 + 10 * M1;        // [10M,26M) overlays xb/wqT/wkT/wvT (dead by then)
  float* pml = (float*)(ws16 + 26 * M1);  // [26M,27M) u16 units = 0.5M floats
  u16* ctx  = qbf;                   // combine writes here after attn

  cvt_bf16<<<8192, 256, 0, stream>>>(x, xb, 8192 * 1024);
  transpose_cvt<<<dim3(32, 32), 256, 0, stream>>>(Wq, wqT, 1024, 1024);
  transpose_cvt<<<dim3(2, 32), 256, 0, stream>>>(Wk, wkT, 1024, 64);
  transpose_cvt<<<dim3(2, 32), 256, 0, stream>>>(Wv, wvT, 1024, 64);
  transpose_cvt<<<dim3(32, 32), 256, 0, stream>>>(Wo, woT, 1024, 1024);

  const float SCL = 0.125f * 1.44269504088896340736f;  // 1/sqrt(Dh) * log2(e) folded into Q
  gemm_bt<0><<<dim3(64, 8), 256, 0, stream>>>(xb, wqT, qbf, nullptr, nullptr, nullptr, SCL);
  gemm_bt<3><<<dim3(64, 1), 256, 0, stream>>>(xb, wkT, k3, vt3, nullptr, nullptr, 1.f);

  attn_mqa3<<<dim3(8, 8, 16), 256, 0, stream>>>(qbf, k3, vt3, paro, pml);
  attn_combine<<<4096, 64, 0, stream>>>(paro, pml, ctx);

  gemm_bt<2><<<dim3(64, 8), 256, 0, stream>>>(ctx, woT, nullptr, nullptr, out, bo, 1.f);
}